// Round 5
// baseline (444.851 us; speedup 1.0000x reference)
//
#include <hip/hip_runtime.h>

// AttentionLayer: N=8, L=1024, D_MODEL=1024, H=16, d_head=64.
// out  = softmax(QK^T/8)V reshaped   (8,1024,1024) fp32
// attn = mean over heads of softmax  (8,1024,1024) fp32, after out.
//
// R5: latency-bound fix. Main loop (loop1) is now BARRIER-FREE: unnormalized
// e=exp(s/8), rsum accumulated on the fly, PV accumulated unnormalized,
// normalization deferred to the epilogue (exact: no max-subtraction needed).
// attn is produced by a recompute pass (loop2) once ir is known; the only
// __syncthreads() live there. One wave per head, block = (n, 16 q), 16 waves.
// ws: 32 MB (bN row-major + bT d-major bf16).

#define NB 8
#define LQ 1024
#define DM 1024
#define NH 16
#define DH 64
#define PW 40           // P32 row stride (shorts): 80 B, breaks pow2
#define AW 68           // attn stage row stride (floats): 272 B

typedef __attribute__((ext_vector_type(4))) float f32x4;
typedef __attribute__((ext_vector_type(8))) short bf16x8;
typedef __attribute__((ext_vector_type(4))) short bf16x4;

__device__ inline short f2bf(float f){
  unsigned u = __builtin_bit_cast(unsigned, f);
  u += 0x7fffu + ((u >> 16) & 1u);   // RNE (inputs finite)
  return (short)(u >> 16);
}

// ---------------- k0: fp32 -> bf16, straight copy + transposed copy ----------
__global__ __launch_bounds__(256) void k0_convert(const float* __restrict__ in,
                                                  short* __restrict__ bN,
                                                  short* __restrict__ bT){
  __shared__ short tile[32][36];
  int b  = blockIdx.x;
  int n  = b >> 10;
  int lt = (b >> 5) & 31;
  int dt = b & 31;
  int r  = threadIdx.x >> 3;
  int c4 = (threadIdx.x & 7) << 2;
  size_t src = ((size_t)(n*LQ + lt*32 + r))*DM + dt*32 + c4;
  f32x4 f = *(const f32x4*)(in + src);
  short s0 = f2bf(f.x), s1 = f2bf(f.y), s2 = f2bf(f.z), s3 = f2bf(f.w);
  bf16x4 pk = {s0, s1, s2, s3};
  *(bf16x4*)(bN + src) = pk;
  tile[c4+0][r] = s0; tile[c4+1][r] = s1; tile[c4+2][r] = s2; tile[c4+3][r] = s3;
  __syncthreads();
  bf16x4 t = *(const bf16x4*)(&tile[r][c4]);
  size_t dst = ((size_t)(n*DM + dt*32 + r))*LQ + lt*32 + c4;
  *(bf16x4*)(bT + dst) = t;
}

// ---------------- k2: one wave per head, barrier-free main loop --------------
__global__ __launch_bounds__(1024, 4) void k2_attn(const short* __restrict__ bN,
                                                   const short* __restrict__ bT,
                                                   float* __restrict__ out,
                                                   float* __restrict__ attn){
  __shared__ float astage[NH*16*AW];    // 69632 B (loop2 only)
  __shared__ short P32[NH*16*PW];       // 20480 B (loop1 only, wave-private rows)
  int tid  = threadIdx.x;
  int lane = tid & 63;
  int w    = tid >> 6;                  // wave id == head id
  int l16  = lane & 15;
  int quad = lane >> 4;
  int n  = blockIdx.x & 7;              // XCD swizzle
  int q0 = (blockIdx.x >> 3) << 4;

  const float CE = 0.1803368801111244f; // 0.125 * log2(e)
  const f32x4 vzero = {0.f, 0.f, 0.f, 0.f};

  const short* qp = bN + ((size_t)(n*LQ + q0 + l16))*DM + w*DH + quad*8;
  bf16x8 qf0 = *(const bf16x8*)qp;
  bf16x8 qf1 = *(const bf16x8*)(qp + 32);

  const short* kbase = bN + ((size_t)(n*LQ + l16))*DM + w*DH + quad*8;
  const short* vbase = bT + ((size_t)(n*DM + w*DH + l16))*LQ + quad*8;

  short* Pmine = &P32[w*16*PW];
  float* Amine = &astage[(size_t)w*16*AW];

  f32x4 oacc[4];
  #pragma unroll
  for (int dt = 0; dt < 4; ++dt) oacc[dt] = vzero;
  float rsum = 0.f;

  // ---- loop1: QK + exp (unnormalized) + PV, NO barriers ----
  bf16x8 kf0 = *(const bf16x8*)kbase;
  bf16x8 kf1 = *(const bf16x8*)(kbase + 32);
  for (int win = 0; win < 16; ++win){
    #pragma unroll
    for (int sub = 0; sub < 4; ++sub){
      // prefetch next 16-s K slice (wraps harmlessly at the end)
      int nidx = (win*64 + sub*16 + 16) & 1023;
      const short* nkp = kbase + (size_t)nidx*DM;
      bf16x8 nkf0 = *(const bf16x8*)nkp;
      bf16x8 nkf1 = *(const bf16x8*)(nkp + 32);
      f32x4 st = vzero;
      st = __builtin_amdgcn_mfma_f32_16x16x32_bf16(kf0, qf0, st, 0, 0, 0);
      st = __builtin_amdgcn_mfma_f32_16x16x32_bf16(kf1, qf1, st, 0, 0, 0);
      float e0 = __builtin_amdgcn_exp2f(st[0]*CE);
      float e1 = __builtin_amdgcn_exp2f(st[1]*CE);
      float e2 = __builtin_amdgcn_exp2f(st[2]*CE);
      float e3 = __builtin_amdgcn_exp2f(st[3]*CE);
      rsum += (e0 + e1) + (e2 + e3);
      bf16x4 pk = {f2bf(e0), f2bf(e1), f2bf(e2), f2bf(e3)};
      *(bf16x4*)(&Pmine[l16*PW + (sub & 1)*16 + quad*4]) = pk;
      if (sub & 1){
        int half = sub >> 1;
        bf16x8 a01 = *(const bf16x8*)(&Pmine[l16*PW + quad*8]);
        #pragma unroll
        for (int dt = 0; dt < 4; ++dt){
          const short* vp = vbase + (size_t)(dt*16)*LQ + win*64 + half*32;
          bf16x8 vf = *(const bf16x8*)vp;
          oacc[dt] = __builtin_amdgcn_mfma_f32_16x16x32_bf16(a01, vf, oacc[dt], 0, 0, 0);
        }
      }
      kf0 = nkf0; kf1 = nkf1;
    }
  }

  // softmax normalizer for q = l16 (full row sum across quads)
  rsum += __shfl_xor(rsum, 16);
  rsum += __shfl_xor(rsum, 32);
  float ir  = 1.0f / rsum;
  float irs = ir * 0.0625f;             // folded 1/NH for attn

  // ---- O epilogue: oacc rows are q = q0 + quad*4 + j -> need ir of that q ----
  float irq[4];
  #pragma unroll
  for (int j = 0; j < 4; ++j) irq[j] = __shfl(ir, quad*4 + j);
  #pragma unroll
  for (int dt = 0; dt < 4; ++dt){
    float* op = out + ((size_t)(n*LQ + q0 + quad*4))*DM + w*DH + dt*16 + l16;
    op[0]      = oacc[dt][0] * irq[0];
    op[DM]     = oacc[dt][1] * irq[1];
    op[2*DM]   = oacc[dt][2] * irq[2];
    op[3*DM]   = oacc[dt][3] * irq[3];
  }

  // ---- loop2: recompute QK per window, scaled attn + cross-head reduce ----
  for (int win = 0; win < 16; ++win){
    // issue all 8 K loads for the window up front
    bf16x8 kw[4][2];
    #pragma unroll
    for (int sub = 0; sub < 4; ++sub){
      const short* kp = kbase + (size_t)(win*64 + sub*16)*DM;
      kw[sub][0] = *(const bf16x8*)kp;
      kw[sub][1] = *(const bf16x8*)(kp + 32);
    }
    #pragma unroll
    for (int sub = 0; sub < 4; ++sub){
      f32x4 st = vzero;
      st = __builtin_amdgcn_mfma_f32_16x16x32_bf16(kw[sub][0], qf0, st, 0, 0, 0);
      st = __builtin_amdgcn_mfma_f32_16x16x32_bf16(kw[sub][1], qf1, st, 0, 0, 0);
      f32x4 av = {__builtin_amdgcn_exp2f(st[0]*CE) * irs,
                  __builtin_amdgcn_exp2f(st[1]*CE) * irs,
                  __builtin_amdgcn_exp2f(st[2]*CE) * irs,
                  __builtin_amdgcn_exp2f(st[3]*CE) * irs};
      *(f32x4*)(&Amine[l16*AW + sub*16 + quad*4]) = av;
    }
    __syncthreads();
    {
      int q = tid >> 6;
      int s = tid & 63;
      float sum = 0.f;
      #pragma unroll
      for (int ww = 0; ww < NH; ++ww)
        sum += astage[(size_t)ww*16*AW + q*AW + s];
      attn[((size_t)(n*LQ + q0 + q))*LQ + win*64 + s] = sum;
    }
    __syncthreads();
  }
}

extern "C" void kernel_launch(void* const* d_in, const int* in_sizes, int n_in,
                              void* d_out, int out_size, void* d_ws, size_t ws_size,
                              hipStream_t stream){
  const float* in = (const float*)d_in[0];
  float* out  = (float*)d_out;
  float* attn = out + (size_t)NB*LQ*DM;
  short* bN = (short*)d_ws;
  short* bT = bN + (size_t)NB*LQ*DM;

  k0_convert<<<dim3(8192), dim3(256),  0, stream>>>(in, bN, bT);
  k2_attn   <<<dim3(512),  dim3(1024), 0, stream>>>(bN, bT, out, attn);
}

// Round 6
// 390.070 us; speedup vs baseline: 1.1404x; 1.1404x over previous
//
#include <hip/hip_runtime.h>

// AttentionLayer: N=8, L=1024, D_MODEL=1024, H=16, d_head=64.
// out  = softmax(QK^T/8)V reshaped   (8,1024,1024) fp32
// attn = mean over heads of softmax  (8,1024,1024) fp32, after out.
//
// R6: coalescing fix. R2-R5 all plateaued ~370-520us with every pipe <15%
// busy; the shared invariant was 2048B-strided fragment loads from global
// (16 scattered segments per instruction -> TA/transaction-bound).
// k0 now emits MFMA-friendly layouts so every fragment load is contiguous:
//   bKw [n][h][s][d=64]          : K/Q fragment pair = contiguous 2KB
//   bTw [n][win32][d=1024][sl=32]: V fragment = contiguous 1KB
// k2 keeps R5's barrier-free loop1 (deferred softmax normalization) and
// loop2 recompute for attn. One wave per head, block = (n, 16 q).
// ws: 32 MB (bKw + bTw).

#define NB 8
#define LQ 1024
#define DM 1024
#define NH 16
#define DH 64
#define PW 40           // P32 row stride (shorts): 80 B, breaks pow2
#define AW 68           // attn stage row stride (floats): 272 B

typedef __attribute__((ext_vector_type(4))) float f32x4;
typedef __attribute__((ext_vector_type(8))) short bf16x8;
typedef __attribute__((ext_vector_type(4))) short bf16x4;

__device__ inline short f2bf(float f){
  unsigned u = __builtin_bit_cast(unsigned, f);
  u += 0x7fffu + ((u >> 16) & 1u);   // RNE (inputs finite)
  return (short)(u >> 16);
}

// ---------------- k0: fp32 -> bf16 into MFMA-friendly layouts ---------------
__global__ __launch_bounds__(256) void k0_convert(const float* __restrict__ in,
                                                  short* __restrict__ bKw,
                                                  short* __restrict__ bTw){
  __shared__ short tile[32][36];
  int b  = blockIdx.x;
  int n  = b >> 10;
  int lt = (b >> 5) & 31;          // s-tile of 32 == V window index
  int dt = b & 31;                 // d-tile of 32: head = dt>>1, half = dt&1
  int r  = threadIdx.x >> 3;       // 0..31
  int c4 = (threadIdx.x & 7) << 2; // 0,4,...,28
  size_t src = ((size_t)(n*LQ + lt*32 + r))*DM + dt*32 + c4;
  f32x4 f = *(const f32x4*)(in + src);
  short s0 = f2bf(f.x), s1 = f2bf(f.y), s2 = f2bf(f.z), s3 = f2bf(f.w);
  // head-major K/Q: bKw[((n*16 + h)*1024 + s)*64 + (dt&1)*32 + c]
  bf16x4 pk = {s0, s1, s2, s3};
  size_t kdst = ((size_t)((n*NH + (dt >> 1))*LQ + lt*32 + r))*DH + (dt & 1)*32 + c4;
  *(bf16x4*)(bKw + kdst) = pk;
  // transpose for V
  tile[c4+0][r] = s0; tile[c4+1][r] = s1; tile[c4+2][r] = s2; tile[c4+3][r] = s3;
  __syncthreads();
  bf16x4 t = *(const bf16x4*)(&tile[r][c4]);
  // win-tiled V: bTw[((n*32 + lt)*1024 + dt*32 + r)*32 + sl]
  size_t vdst = ((size_t)((n*32 + lt)*DM + dt*32 + r))*32 + c4;
  *(bf16x4*)(bTw + vdst) = t;
}

// ---------------- k2: one wave per head, barrier-free main loop --------------
__global__ __launch_bounds__(1024, 4) void k2_attn(const short* __restrict__ bKw,
                                                   const short* __restrict__ bTw,
                                                   float* __restrict__ out,
                                                   float* __restrict__ attn){
  __shared__ float astage[NH*16*AW];    // 69632 B (loop2 only)
  __shared__ short P32[NH*16*PW];       // 20480 B (loop1 only, wave-private rows)
  int tid  = threadIdx.x;
  int lane = tid & 63;
  int w    = tid >> 6;                  // wave id == head id
  int l16  = lane & 15;
  int quad = lane >> 4;
  int n  = blockIdx.x & 7;              // XCD swizzle
  int q0 = (blockIdx.x >> 3) << 4;

  const float CE = 0.1803368801111244f; // 0.125 * log2(e)
  const f32x4 vzero = {0.f, 0.f, 0.f, 0.f};

  // head-major bases: row s -> kb + s*64 (contiguous 2KB per 16-row frag pair)
  const short* kb = bKw + ((size_t)(n*NH + w))*LQ*DH + (size_t)l16*DH + quad*8;
  bf16x8 qf0 = *(const bf16x8*)(kb + (size_t)q0*DH);
  bf16x8 qf1 = *(const bf16x8*)(kb + (size_t)q0*DH + 32);

  short* Pmine = &P32[w*16*PW];
  float* Amine = &astage[(size_t)w*16*AW];

  f32x4 oacc[4];
  #pragma unroll
  for (int dt = 0; dt < 4; ++dt) oacc[dt] = vzero;
  float rsum = 0.f;

  // ---- loop1: QK + exp (unnormalized) + PV, NO barriers ----
  bf16x8 kf0 = *(const bf16x8*)kb;
  bf16x8 kf1 = *(const bf16x8*)(kb + 32);
  for (int win = 0; win < 16; ++win){
    #pragma unroll
    for (int sub = 0; sub < 4; ++sub){
      // prefetch next 16-s K slice (wraps harmlessly at the end)
      int nidx = (win*64 + sub*16 + 16) & 1023;
      const short* nkp = kb + (size_t)nidx*DH;
      bf16x8 nkf0 = *(const bf16x8*)nkp;
      bf16x8 nkf1 = *(const bf16x8*)(nkp + 32);
      f32x4 st = vzero;
      st = __builtin_amdgcn_mfma_f32_16x16x32_bf16(kf0, qf0, st, 0, 0, 0);
      st = __builtin_amdgcn_mfma_f32_16x16x32_bf16(kf1, qf1, st, 0, 0, 0);
      float e0 = __builtin_amdgcn_exp2f(st[0]*CE);
      float e1 = __builtin_amdgcn_exp2f(st[1]*CE);
      float e2 = __builtin_amdgcn_exp2f(st[2]*CE);
      float e3 = __builtin_amdgcn_exp2f(st[3]*CE);
      rsum += (e0 + e1) + (e2 + e3);
      bf16x4 pk = {f2bf(e0), f2bf(e1), f2bf(e2), f2bf(e3)};
      *(bf16x4*)(&Pmine[l16*PW + (sub & 1)*16 + quad*4]) = pk;
      if (sub & 1){
        int vwin = win*2 + (sub >> 1);       // 32-s V window index
        bf16x8 a01 = *(const bf16x8*)(&Pmine[l16*PW + quad*8]);
        #pragma unroll
        for (int dt = 0; dt < 4; ++dt){
          const short* vp = bTw + ((size_t)((n*32 + vwin)*DM + w*DH + dt*16 + l16))*32 + quad*8;
          bf16x8 vf = *(const bf16x8*)vp;
          oacc[dt] = __builtin_amdgcn_mfma_f32_16x16x32_bf16(a01, vf, oacc[dt], 0, 0, 0);
        }
      }
      kf0 = nkf0; kf1 = nkf1;
    }
  }

  // softmax normalizer for q = l16 (full row sum across quads)
  rsum += __shfl_xor(rsum, 16);
  rsum += __shfl_xor(rsum, 32);
  float ir  = 1.0f / rsum;
  float irs = ir * 0.0625f;             // folded 1/NH for attn

  // ---- O epilogue: oacc rows are q = q0 + quad*4 + j -> need ir of that q ----
  float irq[4];
  #pragma unroll
  for (int j = 0; j < 4; ++j) irq[j] = __shfl(ir, quad*4 + j);
  #pragma unroll
  for (int dt = 0; dt < 4; ++dt){
    float* op = out + ((size_t)(n*LQ + q0 + quad*4))*DM + w*DH + dt*16 + l16;
    op[0]      = oacc[dt][0] * irq[0];
    op[DM]     = oacc[dt][1] * irq[1];
    op[2*DM]   = oacc[dt][2] * irq[2];
    op[3*DM]   = oacc[dt][3] * irq[3];
  }

  // ---- loop2: recompute QK per 64-s window, scaled attn + cross-head reduce --
  for (int win = 0; win < 16; ++win){
    bf16x8 kw[4][2];
    #pragma unroll
    for (int sub = 0; sub < 4; ++sub){
      const short* kp = kb + (size_t)(win*64 + sub*16)*DH;
      kw[sub][0] = *(const bf16x8*)kp;
      kw[sub][1] = *(const bf16x8*)(kp + 32);
    }
    #pragma unroll
    for (int sub = 0; sub < 4; ++sub){
      f32x4 st = vzero;
      st = __builtin_amdgcn_mfma_f32_16x16x32_bf16(kw[sub][0], qf0, st, 0, 0, 0);
      st = __builtin_amdgcn_mfma_f32_16x16x32_bf16(kw[sub][1], qf1, st, 0, 0, 0);
      f32x4 av = {__builtin_amdgcn_exp2f(st[0]*CE) * irs,
                  __builtin_amdgcn_exp2f(st[1]*CE) * irs,
                  __builtin_amdgcn_exp2f(st[2]*CE) * irs,
                  __builtin_amdgcn_exp2f(st[3]*CE) * irs};
      *(f32x4*)(&Amine[l16*AW + sub*16 + quad*4]) = av;
    }
    __syncthreads();
    {
      int q = tid >> 6;
      int s = tid & 63;
      float sum = 0.f;
      #pragma unroll
      for (int ww = 0; ww < NH; ++ww)
        sum += astage[(size_t)ww*16*AW + q*AW + s];
      attn[((size_t)(n*LQ + q0 + q))*LQ + win*64 + s] = sum;
    }
    __syncthreads();
  }
}

extern "C" void kernel_launch(void* const* d_in, const int* in_sizes, int n_in,
                              void* d_out, int out_size, void* d_ws, size_t ws_size,
                              hipStream_t stream){
  const float* in = (const float*)d_in[0];
  float* out  = (float*)d_out;
  float* attn = out + (size_t)NB*LQ*DM;
  short* bKw = (short*)d_ws;
  short* bTw = bKw + (size_t)NB*LQ*DM;

  k0_convert<<<dim3(8192), dim3(256),  0, stream>>>(in, bKw, bTw);
  k2_attn   <<<dim3(512),  dim3(1024), 0, stream>>>(bKw, bTw, out, attn);
}